// Round 1
// baseline (3189.846 us; speedup 1.0000x reference)
//
#include <hip/hip_runtime.h>

// Fully-connected e3nn-style tensor product, fp32 VALU version.
// One thread per z-row. x2 row register-resident; weights via wave-uniform
// scalar loads; four pass-loops to bound register pressure / code size.

__global__ __launch_bounds__(256, 2)
void tp_kernel(const float* __restrict__ x1,
               const float* __restrict__ x2,
               const float* __restrict__ w000,
               const float* __restrict__ w011,
               const float* __restrict__ w101,
               const float* __restrict__ w110,
               const float* __restrict__ w111,
               float* __restrict__ out, int n)
{
    int z = blockIdx.x * 256 + threadIdx.x;
    if (z >= n) return;
    const float* __restrict__ x1r = x1 + (size_t)z * 128;
    const float* __restrict__ x2r = x2 + (size_t)z * 128;
    float* __restrict__ outr = out + (size_t)z * 224;

    // A000 = A011 = A101 = A111 = 1/sqrt(2048); A110 = 1/sqrt(6144)
    constexpr float A000 = 0.022097086912079608f;
    constexpr float A011 = 0.022097086912079608f;
    constexpr float A101 = 0.022097086912079608f;
    constexpr float A110 = 0.012757759118834242f;
    constexpr float A111 = 0.022097086912079608f;

    // resident x2 row: scalars + vector components (col = 32 + 3v + i)
    float x2s[32], x2v0[32], x2v1[32], x2v2[32];
#pragma unroll
    for (int v = 0; v < 32; ++v) x2s[v] = x2r[v];
#pragma unroll
    for (int v = 0; v < 32; ++v) {
        x2v0[v] = x2r[32 + 3 * v + 0];
        x2v1[v] = x2r[32 + 3 * v + 1];
        x2v2[v] = x2r[32 + 3 * v + 2];
    }

    // ---------- Pass 0: out0[w] = A000*p000 + A110*p110  (cols 0..31)
    {
        float acc[32];
#pragma unroll
        for (int w = 0; w < 32; ++w) acc[w] = 0.0f;
#pragma unroll 1
        for (int u = 0; u < 32; ++u) {
            float s1 = A000 * x1r[u];
            float p0 = A110 * x1r[32 + 3 * u + 0];
            float p1 = A110 * x1r[32 + 3 * u + 1];
            float p2 = A110 * x1r[32 + 3 * u + 2];
            const float* __restrict__ wa = w000 + u * 1024;
            const float* __restrict__ wb = w110 + u * 1024;
#pragma unroll
            for (int v = 0; v < 32; ++v) {
                float a0 = s1 * x2s[v];
                float d  = p0 * x2v0[v];
                d = fmaf(p1, x2v1[v], d);
                d = fmaf(p2, x2v2[v], d);
                const float* __restrict__ r0 = wa + v * 32;
                const float* __restrict__ r1 = wb + v * 32;
#pragma unroll
                for (int w = 0; w < 32; ++w) {
                    acc[w] = fmaf(a0, r0[w], acc[w]);
                    acc[w] = fmaf(d,  r1[w], acc[w]);
                }
            }
        }
#pragma unroll
        for (int w = 0; w < 32; w += 4)
            *reinterpret_cast<float4*>(outr + w) =
                make_float4(acc[w], acc[w + 1], acc[w + 2], acc[w + 3]);
    }

    // ---------- Pass 1: out1[w,j] = A011*p011 + A101*p101  (cols 32 + 3w + j)
    {
        float acc[96];
#pragma unroll
        for (int t = 0; t < 96; ++t) acc[t] = 0.0f;

        // p101: b_i = (A101*x1v[u,i]) * x2s[v]   (x2s side)
#pragma unroll 1
        for (int u = 0; u < 32; ++u) {
            float b0 = A101 * x1r[32 + 3 * u + 0];
            float b1 = A101 * x1r[32 + 3 * u + 1];
            float b2 = A101 * x1r[32 + 3 * u + 2];
            const float* __restrict__ wa = w101 + u * 1024;
#pragma unroll
            for (int v = 0; v < 32; ++v) {
                float c0 = b0 * x2s[v];
                float c1 = b1 * x2s[v];
                float c2 = b2 * x2s[v];
                const float* __restrict__ r = wa + v * 32;
#pragma unroll
                for (int w = 0; w < 32; ++w) {
                    float wt = r[w];
                    acc[3 * w + 0] = fmaf(c0, wt, acc[3 * w + 0]);
                    acc[3 * w + 1] = fmaf(c1, wt, acc[3 * w + 1]);
                    acc[3 * w + 2] = fmaf(c2, wt, acc[3 * w + 2]);
                }
            }
        }
        // p011: a_j = (A011*x1s[u]) * x2v[v,j]   (x2v side)
#pragma unroll 1
        for (int u = 0; u < 32; ++u) {
            float s1 = A011 * x1r[u];
            const float* __restrict__ wa = w011 + u * 1024;
#pragma unroll
            for (int v = 0; v < 32; ++v) {
                float c0 = s1 * x2v0[v];
                float c1 = s1 * x2v1[v];
                float c2 = s1 * x2v2[v];
                const float* __restrict__ r = wa + v * 32;
#pragma unroll
                for (int w = 0; w < 32; ++w) {
                    float wt = r[w];
                    acc[3 * w + 0] = fmaf(c0, wt, acc[3 * w + 0]);
                    acc[3 * w + 1] = fmaf(c1, wt, acc[3 * w + 1]);
                    acc[3 * w + 2] = fmaf(c2, wt, acc[3 * w + 2]);
                }
            }
        }
#pragma unroll
        for (int t = 0; t < 96; t += 4)
            *reinterpret_cast<float4*>(outr + 32 + t) =
                make_float4(acc[t], acc[t + 1], acc[t + 2], acc[t + 3]);
    }

    // ---------- Pass 2: out2[w,k] = A111 * antisym cross  (cols 128 + 3w + k)
    {
        float acc[96];
#pragma unroll
        for (int t = 0; t < 96; ++t) acc[t] = 0.0f;
#pragma unroll 1
        for (int u = 0; u < 32; ++u) {
            float q0 = A111 * x1r[32 + 3 * u + 0];
            float q1 = A111 * x1r[32 + 3 * u + 1];
            float q2 = A111 * x1r[32 + 3 * u + 2];
            const float* __restrict__ wa = w111 + u * 1024;
#pragma unroll
            for (int v = 0; v < 32; ++v) {
                // k=0:(i=1,j=2), k=1:(2,0), k=2:(0,1)
                float c0 = fmaf(q1, x2v2[v], -(q2 * x2v1[v]));
                float c1 = fmaf(q2, x2v0[v], -(q0 * x2v2[v]));
                float c2 = fmaf(q0, x2v1[v], -(q1 * x2v0[v]));
                const float* __restrict__ r = wa + v * 32;
#pragma unroll
                for (int w = 0; w < 32; ++w) {
                    float wt = r[w];
                    acc[3 * w + 0] = fmaf(c0, wt, acc[3 * w + 0]);
                    acc[3 * w + 1] = fmaf(c1, wt, acc[3 * w + 1]);
                    acc[3 * w + 2] = fmaf(c2, wt, acc[3 * w + 2]);
                }
            }
        }
#pragma unroll
        for (int t = 0; t < 96; t += 4)
            *reinterpret_cast<float4*>(outr + 128 + t) =
                make_float4(acc[t], acc[t + 1], acc[t + 2], acc[t + 3]);
    }
}

extern "C" void kernel_launch(void* const* d_in, const int* in_sizes, int n_in,
                              void* d_out, int out_size, void* d_ws, size_t ws_size,
                              hipStream_t stream) {
    const float* x1   = (const float*)d_in[0];
    const float* x2   = (const float*)d_in[1];
    const float* w000 = (const float*)d_in[2];
    const float* w011 = (const float*)d_in[3];
    const float* w101 = (const float*)d_in[4];
    const float* w110 = (const float*)d_in[5];
    const float* w111 = (const float*)d_in[6];
    float* out = (float*)d_out;

    int n = in_sizes[0] / 128;  // 131072 rows
    dim3 grid((n + 255) / 256), block(256);
    hipLaunchKernelGGL(tp_kernel, grid, block, 0, stream,
                       x1, x2, w000, w011, w101, w110, w111, out, n);
}

// Round 2
// 345.602 us; speedup vs baseline: 9.2298x; 9.2298x over previous
//
#include <hip/hip_runtime.h>

// e3nn fully-connected tensor product via f16 MFMA (16x16x32).
// 11 contractions, each [N x 1024] @ [1024 x 32]; A built on the fly:
// for fixed u, A[z,v] = f1[z,u] * f2[z,v]  (f2 fragment hoisted per GEMM).
// Weights pre-swizzled to MFMA B-fragment order in f16 (scales folded) in ws.

typedef _Float16 f16;
typedef f16 f16x8 __attribute__((ext_vector_type(8)));
typedef float f32x4 __attribute__((ext_vector_type(4)));

#define MFMA16(a, b, c) __builtin_amdgcn_mfma_f32_16x16x32_f16(a, b, c, 0, 0, 0)

// scales: A000=A011=A101=A111=1/sqrt(2048), A110=1/sqrt(6144)
#define SC_COMMON 0.022097086912079608f
#define SC_110    0.012757759118834242f

// ---------------- kernel 0: weight prep -------------------------------------
// ws f16 tensor order: 0=w000, 1=w110, 2=w011, 3=w101, 4=w111 (scale folded).
// Fragment order: idx = c*32768 + u*1024 + half*512 + lane*8 + j
//   element = scale_c * W[u][v = (lane>>4)*8 + j][w = (lane&15) + 16*half]
__global__ void prep_w(const float* __restrict__ w000, const float* __restrict__ w011,
                       const float* __restrict__ w101, const float* __restrict__ w110,
                       const float* __restrict__ w111, f16* __restrict__ wsW)
{
    int flat = blockIdx.x * 256 + threadIdx.x;
    if (flat >= 5 * 32768) return;
    int c = flat >> 15;
    int r = flat & 32767;
    int j    = r & 7;
    int lane = (r >> 3) & 63;
    int half = (r >> 9) & 1;
    int u    = r >> 10;
    int n = lane & 15, q = lane >> 4;
    int v = q * 8 + j;
    int w = n + 16 * half;
    const float* src; float sc;
    switch (c) {
        case 0: src = w000; sc = SC_COMMON; break;
        case 1: src = w110; sc = SC_110;    break;
        case 2: src = w011; sc = SC_COMMON; break;
        case 3: src = w101; sc = SC_COMMON; break;
        default: src = w111; sc = SC_COMMON; break;
    }
    wsW[flat] = (f16)(sc * src[u * 1024 + v * 32 + w]);
}

// ---------------- main kernel ------------------------------------------------
// Block: 256 threads (4 waves), 128 rows. Wave: 32 rows = 2 subtiles of 16.
// LDS: W half-tensor stage (16 u, 32 KB) + x2 feature arrays (32 KB) = 64 KB.

// f1 group: 8 f16 values f1[row][u0..u0+7] read from global x1 (f32) + cvt.
// A==0: x1s (cols 0..31); A==1+i: x1v_i (cols 32+3u+i).
template <int A>
__device__ __forceinline__ f16x8 load_group(const float* __restrict__ x1row, int u0)
{
    f16x8 g;
    if (A == 0) {
#pragma unroll
        for (int j = 0; j < 8; ++j) g[j] = (f16)x1row[u0 + j];
    } else {
#pragma unroll
        for (int j = 0; j < 8; ++j) g[j] = (f16)x1row[32 + 3 * (u0 + j) + (A - 1)];
    }
    return g;
}

// One half-stage (16 u values) of one GEMM.
// MODE 0: simple   A[z,v] = f1(P)[z,u] * f2(Q)[z,v]
// MODE 1: dot      A[z,v] = sum_i x1v_i[z,u] * x2v_i[z,v]
// MODE 2: cross    A[z,v] = x1v(P)[z,u]*x2v(Q)[z,v] - x1v(Q)[z,u]*x2v(P)[z,v]
//                  (P = 1+i, Q = 1+j)
template <int MODE, int P, int Q>
__device__ __forceinline__ void gemm_half(f32x4 (&acc)[2][2],
                                          const f16* __restrict__ ldsW,
                                          const f16* __restrict__ ldsX2,
                                          const float* __restrict__ x1blk,
                                          int waveRow, int lane, int u0base)
{
    const int m = lane & 15, qd = lane >> 4;

    // hoist f2 fragments (per subtile): feat2[row][arr][v = qd*8 .. +7]
    f16x8 f2a[2], f2b[2], f2c[2];
#pragma unroll
    for (int s = 0; s < 2; ++s) {
        const f16* base = ldsX2 + (waveRow + s * 16 + m) * 128 + qd * 8;
        if (MODE == 0) {
            f2a[s] = *(const f16x8*)(base + Q * 32);
        } else if (MODE == 1) {
            f2a[s] = *(const f16x8*)(base + 1 * 32);
            f2b[s] = *(const f16x8*)(base + 2 * 32);
            f2c[s] = *(const f16x8*)(base + 3 * 32);
        } else {
            f2a[s] = *(const f16x8*)(base + Q * 32);  // pairs with f1(P)
            f2b[s] = *(const f16x8*)(base + P * 32);  // pairs with f1(Q), negated
        }
    }

    const float* x1row[2];
#pragma unroll
    for (int s = 0; s < 2; ++s)
        x1row[s] = x1blk + (size_t)(waveRow + s * 16 + m) * 128;

#pragma unroll
    for (int ug = 0; ug < 2; ++ug) {
        const int u0 = u0base + ug * 8;
        f16x8 g1[2], g2[2], g3[2];
#pragma unroll
        for (int s = 0; s < 2; ++s) {
            if (MODE == 0) {
                g1[s] = load_group<P>(x1row[s], u0);
            } else if (MODE == 1) {
                g1[s] = load_group<1>(x1row[s], u0);
                g2[s] = load_group<2>(x1row[s], u0);
                g3[s] = load_group<3>(x1row[s], u0);
            } else {
                g1[s] = load_group<P>(x1row[s], u0);
                g2[s] = load_group<Q>(x1row[s], u0);
            }
        }
#pragma unroll
        for (int uu = 0; uu < 8; ++uu) {
            const int ul = (u0base + ug * 8 + uu) - u0base + (u0base ? 0 : 0); // local u
            const int ulocal = ug * 8 + uu;                                    // 0..15
            (void)ul;
            f16x8 a[2];
#pragma unroll
            for (int s = 0; s < 2; ++s) {
                if (MODE == 0) {
                    a[s] = g1[s][uu] * f2a[s];
                } else if (MODE == 1) {
                    a[s] = g1[s][uu] * f2a[s] + g2[s][uu] * f2b[s] + g3[s][uu] * f2c[s];
                } else {
                    a[s] = g1[s][uu] * f2a[s] - g2[s][uu] * f2b[s];
                }
            }
#pragma unroll
            for (int half = 0; half < 2; ++half) {
                f16x8 b = *(const f16x8*)(ldsW + ((ulocal * 2 + half) * 64 + lane) * 8);
#pragma unroll
                for (int s = 0; s < 2; ++s)
                    acc[s][half] = MFMA16(a[s], b, acc[s][half]);
            }
        }
    }
}

__device__ __forceinline__ void stage_w(f16* __restrict__ ldsW,
                                        const f16* __restrict__ src, int tid)
{
#pragma unroll
    for (int it = 0; it < 8; ++it) {
        int o = it * 2048 + tid * 8;
        *(f16x8*)(ldsW + o) = *(const f16x8*)(src + o);
    }
}

__global__ __launch_bounds__(256, 2)
void tp_main(const float* __restrict__ x1, const float* __restrict__ x2,
             const f16* __restrict__ wsW, float* __restrict__ out)
{
    __shared__ __align__(16) f16 ldsW[16384];   // 32 KB: [u_local][half][lane][j]
    __shared__ __align__(16) f16 ldsX2[16384];  // 32 KB: [row][arr][v], arr: 0=s,1+i=v_i

    const int tid = threadIdx.x;
    const int lane = tid & 63;
    const int wv = tid >> 6;
    const int waveRow = wv * 32;

    const float* x1blk = x1 + (size_t)blockIdx.x * 128 * 128;
    const float* x2blk = x2 + (size_t)blockIdx.x * 128 * 128;

    // ---- stage x2 features into LDS (f16) ----
#pragma unroll
    for (int it = 0; it < 16; ++it) {
        int idx4 = it * 256 + tid;
        float4 val = ((const float4*)x2blk)[idx4];
        float vv[4] = {val.x, val.y, val.z, val.w};
        int flat = idx4 * 4;
        int row = flat >> 7, col = flat & 127;
#pragma unroll
        for (int e = 0; e < 4; ++e) {
            int cc = col + e;
            int arr, ii;
            if (cc < 32) { arr = 0; ii = cc; }
            else { int c2 = cc - 32; arr = 1 + (c2 % 3); ii = c2 / 3; }
            ldsX2[row * 128 + arr * 32 + ii] = (f16)vv[e];
        }
    }

    const int m = lane & 15, qd = lane >> 4;
    const int rowb = blockIdx.x * 128 + waveRow + qd * 4;  // C-layout base row

    // ================= out0: W000 (simple) + W110 (dot) =================
    {
        f32x4 acc[2][2] = {};
        for (int c = 0; c < 2; ++c)
            for (int h = 0; h < 2; ++h) {
                __syncthreads();
                stage_w(ldsW, wsW + c * 32768 + h * 16384, tid);
                __syncthreads();
                if (c == 0) gemm_half<0, 0, 0>(acc, ldsW, ldsX2, x1blk, waveRow, lane, h * 16);
                else        gemm_half<1, 0, 0>(acc, ldsW, ldsX2, x1blk, waveRow, lane, h * 16);
            }
#pragma unroll
        for (int s = 0; s < 2; ++s)
#pragma unroll
            for (int half = 0; half < 2; ++half)
#pragma unroll
                for (int r = 0; r < 4; ++r) {
                    int z = rowb + s * 16 + r;
                    out[(size_t)z * 224 + half * 16 + m] = acc[s][half][r];
                }
    }

    // ================= out1: W011 (p011) + W101 (p101), j = 0..2 =========
    {
        f32x4 acc[3][2][2] = {};
        for (int h = 0; h < 2; ++h) {
            __syncthreads();
            stage_w(ldsW, wsW + 2 * 32768 + h * 16384, tid);
            __syncthreads();
            gemm_half<0, 0, 1>(acc[0], ldsW, ldsX2, x1blk, waveRow, lane, h * 16);
            gemm_half<0, 0, 2>(acc[1], ldsW, ldsX2, x1blk, waveRow, lane, h * 16);
            gemm_half<0, 0, 3>(acc[2], ldsW, ldsX2, x1blk, waveRow, lane, h * 16);
        }
        for (int h = 0; h < 2; ++h) {
            __syncthreads();
            stage_w(ldsW, wsW + 3 * 32768 + h * 16384, tid);
            __syncthreads();
            gemm_half<0, 1, 0>(acc[0], ldsW, ldsX2, x1blk, waveRow, lane, h * 16);
            gemm_half<0, 2, 0>(acc[1], ldsW, ldsX2, x1blk, waveRow, lane, h * 16);
            gemm_half<0, 3, 0>(acc[2], ldsW, ldsX2, x1blk, waveRow, lane, h * 16);
        }
#pragma unroll
        for (int s = 0; s < 2; ++s)
#pragma unroll
            for (int half = 0; half < 2; ++half)
#pragma unroll
                for (int r = 0; r < 4; ++r) {
                    int z = rowb + s * 16 + r;
                    int wcol = half * 16 + m;
                    size_t base = (size_t)z * 224 + 32 + 3 * wcol;
                    out[base + 0] = acc[0][s][half][r];
                    out[base + 1] = acc[1][s][half][r];
                    out[base + 2] = acc[2][s][half][r];
                }
    }

    // ================= out2: W111 cross, k = 0..2 ========================
    // k=0:(i,j)=(1,2) -> P=2,Q=3 ; k=1:(2,0) -> P=3,Q=1 ; k=2:(0,1) -> P=1,Q=2
    {
        f32x4 acc[3][2][2] = {};
        for (int h = 0; h < 2; ++h) {
            __syncthreads();
            stage_w(ldsW, wsW + 4 * 32768 + h * 16384, tid);
            __syncthreads();
            gemm_half<2, 2, 3>(acc[0], ldsW, ldsX2, x1blk, waveRow, lane, h * 16);
            gemm_half<2, 3, 1>(acc[1], ldsW, ldsX2, x1blk, waveRow, lane, h * 16);
            gemm_half<2, 1, 2>(acc[2], ldsW, ldsX2, x1blk, waveRow, lane, h * 16);
        }
#pragma unroll
        for (int s = 0; s < 2; ++s)
#pragma unroll
            for (int half = 0; half < 2; ++half)
#pragma unroll
                for (int r = 0; r < 4; ++r) {
                    int z = rowb + s * 16 + r;
                    int wcol = half * 16 + m;
                    size_t base = (size_t)z * 224 + 128 + 3 * wcol;
                    out[base + 0] = acc[0][s][half][r];
                    out[base + 1] = acc[1][s][half][r];
                    out[base + 2] = acc[2][s][half][r];
                }
    }
}

// ---------------- launch -----------------------------------------------------
extern "C" void kernel_launch(void* const* d_in, const int* in_sizes, int n_in,
                              void* d_out, int out_size, void* d_ws, size_t ws_size,
                              hipStream_t stream)
{
    const float* x1   = (const float*)d_in[0];
    const float* x2   = (const float*)d_in[1];
    const float* w000 = (const float*)d_in[2];
    const float* w011 = (const float*)d_in[3];
    const float* w101 = (const float*)d_in[4];
    const float* w110 = (const float*)d_in[5];
    const float* w111 = (const float*)d_in[6];
    float* out = (float*)d_out;
    f16* wsW = (f16*)d_ws;

    // prep weights: 5 * 32768 f16 = 320 KB in ws
    hipLaunchKernelGGL(prep_w, dim3(640), dim3(256), 0, stream,
                       w000, w011, w101, w110, w111, wsW);

    int n = in_sizes[0] / 128;  // 131072 rows
    hipLaunchKernelGGL(tp_main, dim3(n / 128), dim3(256), 0, stream,
                       x1, x2, wsW, out);
}

// Round 3
// 292.262 us; speedup vs baseline: 10.9143x; 1.1825x over previous
//
#include <hip/hip_runtime.h>

// e3nn fully-connected tensor product, v3: f16 MFMA 32x32x16.
// One wave owns 32 rows (lane&31 = its row). x1/x2 features live in
// registers (loaded once, coalesced float4); LDS holds only the current
// 16-u half of one weight tensor (32 KB), staged via global_load_lds and
// read as lane-contiguous ds_read_b128 (conflict-free, immediate offsets).
// B fragments are shared across the 3 accumulators of 3-GEMM phases.

typedef _Float16 f16;
typedef f16 f16x8 __attribute__((ext_vector_type(8)));
typedef float f32x16 __attribute__((ext_vector_type(16)));

#define MFMA32(a, b, c) __builtin_amdgcn_mfma_f32_32x32x16_f16(a, b, c, 0, 0, 0)

// A000 = A011 = A101 = A111 = 1/sqrt(2048); A110 = 1/sqrt(6144)
#define SC_COMMON 0.022097086912079608f
#define SC_110    0.012757759118834242f

// ---------------- weight prep ------------------------------------------------
// ws order: c0=w000, c1=w110, c2=w011, c3=w101, c4=w111 (scales folded).
// B-frag (32x32x16): lane holds B[k=(lane>>5)*8+j][n=lane&31], K-chunk vh.
// idx = ((c*32 + u)*2 + vh)*512 + lane*8 + j
//   element = sc * W[u][ v = vh*16 + (lane>>5)*8 + j ][ w = lane&31 ]
__global__ void prep_w(const float* __restrict__ w000, const float* __restrict__ w011,
                       const float* __restrict__ w101, const float* __restrict__ w110,
                       const float* __restrict__ w111, f16* __restrict__ wsW)
{
    int flat = blockIdx.x * 256 + threadIdx.x;
    if (flat >= 5 * 32768) return;
    int c    = flat >> 15;
    int r    = flat & 32767;
    int j    = r & 7;
    int lane = (r >> 3) & 63;
    int vh   = (r >> 9) & 1;
    int u    = r >> 10;
    int v = vh * 16 + ((lane >> 5) << 3) + j;
    int w = lane & 31;
    const float* src; float sc;
    switch (c) {
        case 0: src = w000; sc = SC_COMMON; break;
        case 1: src = w110; sc = SC_110;    break;
        case 2: src = w011; sc = SC_COMMON; break;
        case 3: src = w101; sc = SC_COMMON; break;
        default: src = w111; sc = SC_COMMON; break;
    }
    wsW[flat] = (f16)(sc * src[u * 1024 + v * 32 + w]);
}

// ---------------- main kernel ------------------------------------------------
// MODE: 0 = w000 (s*s), 1 = w110 (vec dot), 2 = w011 (p011, 3 acc),
//       3 = w101 (p101, 3 acc), 4 = w111 (cross, 3 acc)
template <int U0, int MODE, int NA>
__device__ __forceinline__ void do_stage(f32x16 (&acc)[NA],
                                         const f16* __restrict__ ldsW,
                                         const f16x8 (&f1g)[4][4],
                                         const f16x8 (&f2g)[4][2], int lane)
{
#pragma unroll
    for (int ul = 0; ul < 16; ++ul) {
        const int u = U0 + ul;
#pragma unroll
        for (int vh = 0; vh < 2; ++vh) {
            f16x8 b = *(const f16x8*)(ldsW + ul * 1024 + vh * 512 + lane * 8);
            if (MODE == 0) {
                f16x8 a = f1g[0][u >> 3][u & 7] * f2g[0][vh];
                acc[0] = MFMA32(a, b, acc[0]);
            } else if (MODE == 1) {
                f16x8 a = f1g[1][u >> 3][u & 7] * f2g[1][vh];
                a += f1g[2][u >> 3][u & 7] * f2g[2][vh];
                a += f1g[3][u >> 3][u & 7] * f2g[3][vh];
                acc[0] = MFMA32(a, b, acc[0]);
            } else if (MODE == 2) {
#pragma unroll
                for (int j = 0; j < 3; ++j) {
                    f16x8 a = f1g[0][u >> 3][u & 7] * f2g[1 + j][vh];
                    acc[j] = MFMA32(a, b, acc[j]);
                }
            } else if (MODE == 3) {
#pragma unroll
                for (int j = 0; j < 3; ++j) {
                    f16x8 a = f1g[1 + j][u >> 3][u & 7] * f2g[0][vh];
                    acc[j] = MFMA32(a, b, acc[j]);
                }
            } else {
                // cross: k0:(i=1,j=2)->arrs(2,3); k1:(2,0)->(3,1); k2:(0,1)->(1,2)
#pragma unroll
                for (int k = 0; k < 3; ++k) {
                    const int P = (k == 0) ? 2 : (k == 1) ? 3 : 1;
                    const int Q = (k == 0) ? 3 : (k == 1) ? 1 : 2;
                    f16x8 a = f1g[P][u >> 3][u & 7] * f2g[Q][vh]
                            - f1g[Q][u >> 3][u & 7] * f2g[P][vh];
                    acc[k] = MFMA32(a, b, acc[k]);
                }
            }
        }
    }
}

__global__ __launch_bounds__(256, 2)
void tp_main(const float* __restrict__ x1, const float* __restrict__ x2,
             const f16* __restrict__ wsW, float* __restrict__ out)
{
    __shared__ __align__(16) f16 ldsW[16384];  // 32 KB: one 16-u half-tensor

    const int tid = threadIdx.x, lane = tid & 63, wv = tid >> 6;
    const int rowBase = blockIdx.x * 128 + wv * 32;
    const int mrow = lane & 31;          // this lane's row (A and C/D)
    const int half = lane >> 5;          // k-group
    const int klo = half * 8;
    const float4* x1r4 = (const float4*)(x1 + (size_t)(rowBase + mrow) * 128);
    const float4* x2r4 = (const float4*)(x2 + (size_t)(rowBase + mrow) * 128);

    // ---- f1: all 128 features of my row, f16, [arr][u] ----
    f16x8 f1g[4][4];
    {
        float b0[32];
#pragma unroll
        for (int g = 0; g < 8; ++g) ((float4*)b0)[g] = x1r4[g];
#pragma unroll
        for (int g = 0; g < 4; ++g)
#pragma unroll
            for (int j = 0; j < 8; ++j) f1g[0][g][j] = (f16)b0[g * 8 + j];
        float b1[96];
#pragma unroll
        for (int g = 0; g < 24; ++g) ((float4*)b1)[g] = x1r4[8 + g];
#pragma unroll
        for (int i = 0; i < 3; ++i)
#pragma unroll
            for (int g = 0; g < 4; ++g)
#pragma unroll
                for (int j = 0; j < 8; ++j)
                    f1g[1 + i][g][j] = (f16)b1[3 * (g * 8 + j) + i];
    }

    // ---- f2: my row's k-slice: v = vh*16 + klo + j, [arr][vh] ----
    f16x8 f2g[4][2];
    {
        float c0[16];
#pragma unroll
        for (int g = 0; g < 2; ++g) ((float4*)c0)[g]     = x2r4[klo / 4 + g];
#pragma unroll
        for (int g = 0; g < 2; ++g) ((float4*)c0)[2 + g] = x2r4[4 + klo / 4 + g];
#pragma unroll
        for (int vh = 0; vh < 2; ++vh)
#pragma unroll
            for (int j = 0; j < 8; ++j) f2g[0][vh][j] = (f16)c0[vh * 8 + j];
        // vec spans: floats [32+3*klo, +24) and [80+3*klo, +24), both 16B-aligned
        float c1[48];
        const int base1 = (32 + 3 * klo) / 4;
#pragma unroll
        for (int g = 0; g < 6; ++g) ((float4*)c1)[g]     = x2r4[base1 + g];
#pragma unroll
        for (int g = 0; g < 6; ++g) ((float4*)c1)[6 + g] = x2r4[base1 + 12 + g];
#pragma unroll
        for (int i = 0; i < 3; ++i)
#pragma unroll
            for (int vh = 0; vh < 2; ++vh)
#pragma unroll
                for (int j = 0; j < 8; ++j)
                    f2g[1 + i][vh][j] = (f16)c1[vh * 24 + 3 * j + i];
    }

    // ---- weight staging: 32 KB per (c, h) via global_load_lds width 16 ----
    auto stage = [&](int c, int h) {
        __syncthreads();  // previous stage's reads complete before overwrite
        const f16* src = wsW + c * 32768 + h * 16384;
#pragma unroll
        for (int it = 0; it < 8; ++it) {
            int o = (it * 256 + tid) * 8;
            __builtin_amdgcn_global_load_lds(
                (const __attribute__((address_space(1))) void*)(src + o),
                (__attribute__((address_space(3))) void*)(ldsW + o), 16, 0, 0);
        }
        __syncthreads();  // drains vmcnt, data visible
    };

    // ================= out0: w000 + w110 =================
    {
        f32x16 acc[1] = {};
        stage(0, 0); do_stage<0, 0>(acc, ldsW, f1g, f2g, lane);
        stage(0, 1); do_stage<16, 0>(acc, ldsW, f1g, f2g, lane);
        stage(1, 0); do_stage<0, 1>(acc, ldsW, f1g, f2g, lane);
        stage(1, 1); do_stage<16, 1>(acc, ldsW, f1g, f2g, lane);
#pragma unroll
        for (int reg = 0; reg < 16; ++reg) {
            int r = (reg & 3) + 8 * (reg >> 2) + 4 * half;
            out[(size_t)(rowBase + r) * 224 + mrow] = acc[0][reg];
        }
    }
    // ================= out1: w011 (p011) + w101 (p101) =================
    {
        f32x16 acc[3] = {};
        stage(2, 0); do_stage<0, 2>(acc, ldsW, f1g, f2g, lane);
        stage(2, 1); do_stage<16, 2>(acc, ldsW, f1g, f2g, lane);
        stage(3, 0); do_stage<0, 3>(acc, ldsW, f1g, f2g, lane);
        stage(3, 1); do_stage<16, 3>(acc, ldsW, f1g, f2g, lane);
#pragma unroll
        for (int reg = 0; reg < 16; ++reg) {
            int r = (reg & 3) + 8 * (reg >> 2) + 4 * half;
            size_t base = (size_t)(rowBase + r) * 224 + 32 + 3 * mrow;
            out[base + 0] = acc[0][reg];
            out[base + 1] = acc[1][reg];
            out[base + 2] = acc[2][reg];
        }
    }
    // ================= out2: w111 (cross) =================
    {
        f32x16 acc[3] = {};
        stage(4, 0); do_stage<0, 4>(acc, ldsW, f1g, f2g, lane);
        stage(4, 1); do_stage<16, 4>(acc, ldsW, f1g, f2g, lane);
#pragma unroll
        for (int reg = 0; reg < 16; ++reg) {
            int r = (reg & 3) + 8 * (reg >> 2) + 4 * half;
            size_t base = (size_t)(rowBase + r) * 224 + 128 + 3 * mrow;
            out[base + 0] = acc[0][reg];
            out[base + 1] = acc[1][reg];
            out[base + 2] = acc[2][reg];
        }
    }
}

// ---------------- launch -----------------------------------------------------
extern "C" void kernel_launch(void* const* d_in, const int* in_sizes, int n_in,
                              void* d_out, int out_size, void* d_ws, size_t ws_size,
                              hipStream_t stream)
{
    const float* x1   = (const float*)d_in[0];
    const float* x2   = (const float*)d_in[1];
    const float* w000 = (const float*)d_in[2];
    const float* w011 = (const float*)d_in[3];
    const float* w101 = (const float*)d_in[4];
    const float* w110 = (const float*)d_in[5];
    const float* w111 = (const float*)d_in[6];
    float* out = (float*)d_out;
    f16* wsW = (f16*)d_ws;  // 5 * 32768 f16 = 320 KB

    hipLaunchKernelGGL(prep_w, dim3(640), dim3(256), 0, stream,
                       w000, w011, w101, w110, w111, wsW);

    int n = in_sizes[0] / 128;  // 131072 rows
    hipLaunchKernelGGL(tp_main, dim3(n / 128), dim3(256), 0, stream,
                       x1, x2, wsW, out);
}